// Round 7
// baseline (295.395 us; speedup 1.0000x reference)
//
#include <hip/hip_runtime.h>
#include <math.h>

// Problem constants (fixed by the reference).
#define B_ 256
#define J_ 10
#define I_ 1152
#define N_ 16
#define TPB 512    // 8 waves; one block per batch element; grid = 256 = 1/CU
#define ROWS 128   // i-rows per step = TPB/4
#define STEPS 9    // I_ / ROWS

__device__ __forceinline__ float4 ld4(const float* p) {
  return *(const float4*)p;
}

__device__ __forceinline__ float squash16(float s) {
  // 16 pose components live in a 16-lane group (n = lane&15).
  float sq = s * s;
  sq += __shfl_xor(sq, 1);
  sq += __shfl_xor(sq, 2);
  sq += __shfl_xor(sq, 4);
  sq += __shfl_xor(sq, 8);
  return (sq / (1.f + sq)) * s * rsqrtf(sq + 1e-8f);
}

// Load one step's tile: 10 x float4 (all j at row i), independent loads.
__device__ __forceinline__ void load_tile(const float* __restrict__ base,
                                          int i, float4* t) {
#pragma unroll
  for (int j = 0; j < J_; ++j) t[j] = ld4(base + ((size_t)j * I_ + i) * N_);
}

__device__ __forceinline__ void sum_tile(const float4* t, float4* acc) {
#pragma unroll
  for (int j = 0; j < J_; ++j) {
    acc[j].x += t[j].x;
    acc[j].y += t[j].y;
    acc[j].z += t[j].z;
    acc[j].w += t[j].w;
  }
}

// acc[j] += softmax_j(u.w + mv) * u for this tile. No max-subtract: |u.w| is
// O(10) << 88 (fp32 exp range), and masked j (mv=-1e30) gives exp()=0 exactly.
__device__ __forceinline__ void w_tile(const float4* t, const float4* wq,
                                       const float* mvj, float4* acc) {
  float e[J_];
  float se = 0.f;
#pragma unroll
  for (int j = 0; j < J_; ++j) {
    float d = t[j].x * wq[j].x + t[j].y * wq[j].y + t[j].z * wq[j].z +
              t[j].w * wq[j].w;
    d += __shfl_xor(d, 1);  // sum the 4 n-quads -> full 16-dot
    d += __shfl_xor(d, 2);
    e[j] = __expf(d + mvj[j]);
    se += e[j];
  }
  const float inv = 1.f / se;
#pragma unroll
  for (int j = 0; j < J_; ++j) {
    const float c = e[j] * inv;
    acc[j].x = fmaf(c, t[j].x, acc[j].x);
    acc[j].y = fmaf(c, t[j].y, acc[j].y);
    acc[j].z = fmaf(c, t[j].z, acc[j].z);
    acc[j].w = fmaf(c, t[j].w, acc[j].w);
  }
}

// Reduce acc[J] (per-thread float4 over rows x q) into red[J][8][16].
__device__ __forceinline__ void block_reduce(const float4* acc,
                                             float* __restrict__ red,
                                             int tid) {
  const int lane = tid & 63;
  const int wv = tid >> 6;
#pragma unroll
  for (int j = 0; j < J_; ++j) {
    float4 a = acc[j];
#pragma unroll
    for (int off = 4; off < 64; off <<= 1) {
      a.x += __shfl_xor(a.x, off);
      a.y += __shfl_xor(a.y, off);
      a.z += __shfl_xor(a.z, off);
      a.w += __shfl_xor(a.w, off);
    }
    if (lane < 4) {  // lane == q for lanes 0..3
      red[(j * 8 + wv) * 16 + lane * 4 + 0] = a.x;
      red[(j * 8 + wv) * 16 + lane * 4 + 1] = a.y;
      red[(j * 8 + wv) * 16 + lane * 4 + 2] = a.z;
      red[(j * 8 + wv) * 16 + lane * 4 + 3] = a.w;
    }
  }
  __syncthreads();
}

__device__ __forceinline__ float red_sum(const float* __restrict__ red, int j,
                                         int n) {
  float s = 0.f;
#pragma unroll
  for (int w = 0; w < 8; ++w) s += red[(j * 8 + w) * 16 + n];
  return s;
}

__global__ __launch_bounds__(TPB) void routing_one(
    const float* __restrict__ u, const float* __restrict__ bias,
    float* __restrict__ out) {
  const int tid = threadIdx.x;
  const int q = tid & 3;    // n-quad
  const int il = tid >> 2;  // local i row 0..127
  const int b = blockIdx.x;
  const float* base = u + (size_t)b * J_ * I_ * N_ + q * 4;

  __shared__ float red[J_ * 8 * 16];
  __shared__ float wsh[J_ * N_];   // current w (v0, then v0+v1)
  __shared__ float v0sh[J_ * N_];  // v0
  __shared__ float S0sh[J_ * N_];  // S0 = sum_i u
  __shared__ float avg[J_];
  __shared__ float thr_s;

  float4 A[J_], Bf[J_], acc[J_];

  // ---- pass 0: S0 = sum_i u (double-buffered prefetch) -------------------
  load_tile(base, il, A);
#pragma unroll
  for (int j = 0; j < J_; ++j) acc[j] = make_float4(0.f, 0.f, 0.f, 0.f);
#pragma unroll
  for (int p = 0; p < STEPS; p += 2) {
    if (p + 1 < STEPS) load_tile(base, (p + 1) * ROWS + il, Bf);
    sum_tile(A, acc);
    if (p + 2 < STEPS) load_tile(base, (p + 2) * ROWS + il, A);
    if (p + 1 < STEPS) sum_tile(Bf, acc);
  }
  load_tile(base, il, A);  // prefetch pass-1 step 0 under the reduction
  block_reduce(acc, red, tid);
  if (tid < J_ * N_) {
    const int j = tid >> 4, n = tid & 15;
    const float S0 = red_sum(red, j, n);
    S0sh[tid] = S0;
    const float v0 = squash16(S0 * (1.f / (float)J_) + bias[j * N_ + n]);
    v0sh[tid] = v0;
    wsh[tid] = v0;
  }
  __syncthreads();

  float4 wq[J_];
  float mvj[J_];
#pragma unroll
  for (int j = 0; j < J_; ++j) {
    wq[j] = ld4(&wsh[j * N_ + q * 4]);
    mvj[j] = 0.f;
  }

  // ---- pass 1: c = softmax_j(u.v0); v1 = squash(s1+bias); threshold ------
#pragma unroll
  for (int j = 0; j < J_; ++j) acc[j] = make_float4(0.f, 0.f, 0.f, 0.f);
#pragma unroll
  for (int p = 0; p < STEPS; p += 2) {
    if (p + 1 < STEPS) load_tile(base, (p + 1) * ROWS + il, Bf);
    w_tile(A, wq, mvj, acc);
    if (p + 2 < STEPS) load_tile(base, (p + 2) * ROWS + il, A);
    if (p + 1 < STEPS) w_tile(Bf, wq, mvj, acc);
  }
  load_tile(base, il, A);  // prefetch pass-2 step 0 under the reduction
  block_reduce(acc, red, tid);
  if (tid < J_ * N_) {
    const int j = tid >> 4, n = tid & 15;
    const float s1 = red_sum(red, j, n) + bias[j * N_ + n];
    const float v1 = squash16(s1);
    const float w2 = v0sh[tid] + v1;
    wsh[tid] = w2;
    float pa = S0sh[tid] * w2;
    pa += __shfl_xor(pa, 1);
    pa += __shfl_xor(pa, 2);
    pa += __shfl_xor(pa, 4);
    pa += __shfl_xor(pa, 8);
    if (n == 0) avg[j] = pa * (1.f / (float)I_);
  }
  __syncthreads();
  if (tid == 0) {
    float a = avg[0];
    for (int jj = 1; jj < J_; ++jj) a = fmaxf(a, avg[jj]);
    float se = 0.f;
    for (int jj = 0; jj < J_; ++jj) se += expf(avg[jj] - a);
    thr_s = logf(0.1f) + a + logf(se);
  }
  __syncthreads();
#pragma unroll
  for (int j = 0; j < J_; ++j) {
    wq[j] = ld4(&wsh[j * N_ + q * 4]);
    mvj[j] = (avg[j] < thr_s) ? -1e30f : 0.f;
  }

  // ---- pass 2: c = softmax_j(u.w + mv); out = del ? 0 : squash(s2) -------
#pragma unroll
  for (int j = 0; j < J_; ++j) acc[j] = make_float4(0.f, 0.f, 0.f, 0.f);
#pragma unroll
  for (int p = 0; p < STEPS; p += 2) {
    if (p + 1 < STEPS) load_tile(base, (p + 1) * ROWS + il, Bf);
    w_tile(A, wq, mvj, acc);
    if (p + 2 < STEPS) load_tile(base, (p + 2) * ROWS + il, A);
    if (p + 1 < STEPS) w_tile(Bf, wq, mvj, acc);
  }
  block_reduce(acc, red, tid);
  if (tid < J_ * N_) {
    const int j = tid >> 4, n = tid & 15;
    const float s2 = red_sum(red, j, n) + bias[j * N_ + n];
    const float v2 = squash16(s2);
    const bool del = avg[j] < thr_s;
    out[(b * J_ + j) * N_ + n] = del ? 0.f : v2;
  }
}

extern "C" void kernel_launch(void* const* d_in, const int* in_sizes, int n_in,
                              void* d_out, int out_size, void* d_ws,
                              size_t ws_size, hipStream_t stream) {
  const float* u = (const float*)d_in[0];     // [B,J,I,N]
  const float* bias = (const float*)d_in[1];  // [J,N]
  // d_in[2] = iters (always 3; structure hardcoded)
  float* out = (float*)d_out;
  routing_one<<<B_, TPB, 0, stream>>>(u, bias, out);
}

// Round 8
// 295.063 us; speedup vs baseline: 1.0011x; 1.0011x over previous
//
#include <hip/hip_runtime.h>
#include <math.h>

// Problem constants (fixed by the reference).
#define B_ 256
#define J_ 10
#define I_ 1152
#define N_ 16
#define TPB 512    // 8 waves; one block per batch element; grid = 256 = 1/CU
#define ROWS 128   // i-rows per step = TPB/4
#define STEPS 9    // I_ / ROWS

__device__ __forceinline__ float4 ld4(const float* p) {
  return *(const float4*)p;
}

__device__ __forceinline__ float squash16(float s) {
  // 16 pose components live in a 16-lane group (n = lane&15).
  float sq = s * s;
  sq += __shfl_xor(sq, 1);
  sq += __shfl_xor(sq, 2);
  sq += __shfl_xor(sq, 4);
  sq += __shfl_xor(sq, 8);
  return (sq / (1.f + sq)) * s * rsqrtf(sq + 1e-8f);
}

// Load one step's tile: 10 x float4 (all j at row i), independent loads.
__device__ __forceinline__ void load_tile(const float* __restrict__ base,
                                          int i, float4* t) {
#pragma unroll
  for (int j = 0; j < J_; ++j) t[j] = ld4(base + ((size_t)j * I_ + i) * N_);
}

__device__ __forceinline__ void sum_tile(const float4* t, float4* acc) {
#pragma unroll
  for (int j = 0; j < J_; ++j) {
    acc[j].x += t[j].x;
    acc[j].y += t[j].y;
    acc[j].z += t[j].z;
    acc[j].w += t[j].w;
  }
}

// acc[j] += softmax_j(u.w + mv) * u for this tile. No max-subtract: |u.w| is
// O(10) << 88 (fp32 exp range), and masked j (mv=-1e30) gives exp()=0 exactly.
__device__ __forceinline__ void w_tile(const float4* t, const float4* wq,
                                       const float* mvj, float4* acc) {
  float e[J_];
  float se = 0.f;
#pragma unroll
  for (int j = 0; j < J_; ++j) {
    float d = t[j].x * wq[j].x + t[j].y * wq[j].y + t[j].z * wq[j].z +
              t[j].w * wq[j].w;
    d += __shfl_xor(d, 1);  // sum the 4 n-quads -> full 16-dot
    d += __shfl_xor(d, 2);
    e[j] = __expf(d + mvj[j]);
    se += e[j];
  }
  const float inv = 1.f / se;
#pragma unroll
  for (int j = 0; j < J_; ++j) {
    const float c = e[j] * inv;
    acc[j].x = fmaf(c, t[j].x, acc[j].x);
    acc[j].y = fmaf(c, t[j].y, acc[j].y);
    acc[j].z = fmaf(c, t[j].z, acc[j].z);
    acc[j].w = fmaf(c, t[j].w, acc[j].w);
  }
}

// Reduce acc[J] (per-thread float4 over rows x q) into red[J][8][16].
__device__ __forceinline__ void block_reduce(const float4* acc,
                                             float* __restrict__ red,
                                             int tid) {
  const int lane = tid & 63;
  const int wv = tid >> 6;
#pragma unroll
  for (int j = 0; j < J_; ++j) {
    float4 a = acc[j];
#pragma unroll
    for (int off = 4; off < 64; off <<= 1) {
      a.x += __shfl_xor(a.x, off);
      a.y += __shfl_xor(a.y, off);
      a.z += __shfl_xor(a.z, off);
      a.w += __shfl_xor(a.w, off);
    }
    if (lane < 4) {  // lane == q for lanes 0..3
      red[(j * 8 + wv) * 16 + lane * 4 + 0] = a.x;
      red[(j * 8 + wv) * 16 + lane * 4 + 1] = a.y;
      red[(j * 8 + wv) * 16 + lane * 4 + 2] = a.z;
      red[(j * 8 + wv) * 16 + lane * 4 + 3] = a.w;
    }
  }
  __syncthreads();
}

__device__ __forceinline__ float red_sum(const float* __restrict__ red, int j,
                                         int n) {
  float s = 0.f;
#pragma unroll
  for (int w = 0; w < 8; ++w) s += red[(j * 8 + w) * 16 + n];
  return s;
}

__global__ __launch_bounds__(TPB)
__attribute__((amdgpu_waves_per_eu(2))) void routing_one(
    const float* __restrict__ u, const float* __restrict__ bias,
    float* __restrict__ out) {
  const int tid = threadIdx.x;
  const int q = tid & 3;    // n-quad
  const int il = tid >> 2;  // local i row 0..127
  const int b = blockIdx.x;
  const float* base = u + (size_t)b * J_ * I_ * N_ + q * 4;

  __shared__ float red[J_ * 8 * 16];
  __shared__ float wsh[J_ * N_];   // current w (v0, then v0+v1)
  __shared__ float v0sh[J_ * N_];  // v0
  __shared__ float S0sh[J_ * N_];  // S0 = sum_i u
  __shared__ float avg[J_];
  __shared__ float thr_s;

  float4 A[J_], Bf[J_], acc[J_];

  // ---- pass 0: S0 = sum_i u (double-buffered prefetch) -------------------
  load_tile(base, il, A);
#pragma unroll
  for (int j = 0; j < J_; ++j) acc[j] = make_float4(0.f, 0.f, 0.f, 0.f);
#pragma unroll
  for (int p = 0; p < STEPS; p += 2) {
    if (p + 1 < STEPS) load_tile(base, (p + 1) * ROWS + il, Bf);
    sum_tile(A, acc);
    if (p + 2 < STEPS) load_tile(base, (p + 2) * ROWS + il, A);
    if (p + 1 < STEPS) sum_tile(Bf, acc);
  }
  load_tile(base, il, A);  // prefetch pass-1 step 0 under the reduction
  block_reduce(acc, red, tid);
  if (tid < J_ * N_) {
    const int j = tid >> 4, n = tid & 15;
    const float S0 = red_sum(red, j, n);
    S0sh[tid] = S0;
    const float v0 = squash16(S0 * (1.f / (float)J_) + bias[j * N_ + n]);
    v0sh[tid] = v0;
    wsh[tid] = v0;
  }
  __syncthreads();

  float4 wq[J_];
  float mvj[J_];
#pragma unroll
  for (int j = 0; j < J_; ++j) {
    wq[j] = ld4(&wsh[j * N_ + q * 4]);
    mvj[j] = 0.f;
  }

  // ---- pass 1: c = softmax_j(u.v0); v1 = squash(s1+bias); threshold ------
#pragma unroll
  for (int j = 0; j < J_; ++j) acc[j] = make_float4(0.f, 0.f, 0.f, 0.f);
#pragma unroll
  for (int p = 0; p < STEPS; p += 2) {
    if (p + 1 < STEPS) load_tile(base, (p + 1) * ROWS + il, Bf);
    w_tile(A, wq, mvj, acc);
    if (p + 2 < STEPS) load_tile(base, (p + 2) * ROWS + il, A);
    if (p + 1 < STEPS) w_tile(Bf, wq, mvj, acc);
  }
  load_tile(base, il, A);  // prefetch pass-2 step 0 under the reduction
  block_reduce(acc, red, tid);
  if (tid < J_ * N_) {
    const int j = tid >> 4, n = tid & 15;
    const float s1 = red_sum(red, j, n) + bias[j * N_ + n];
    const float v1 = squash16(s1);
    const float w2 = v0sh[tid] + v1;
    wsh[tid] = w2;
    float pa = S0sh[tid] * w2;
    pa += __shfl_xor(pa, 1);
    pa += __shfl_xor(pa, 2);
    pa += __shfl_xor(pa, 4);
    pa += __shfl_xor(pa, 8);
    if (n == 0) avg[j] = pa * (1.f / (float)I_);
  }
  __syncthreads();
  if (tid == 0) {
    float a = avg[0];
    for (int jj = 1; jj < J_; ++jj) a = fmaxf(a, avg[jj]);
    float se = 0.f;
    for (int jj = 0; jj < J_; ++jj) se += expf(avg[jj] - a);
    thr_s = logf(0.1f) + a + logf(se);
  }
  __syncthreads();
#pragma unroll
  for (int j = 0; j < J_; ++j) {
    wq[j] = ld4(&wsh[j * N_ + q * 4]);
    mvj[j] = (avg[j] < thr_s) ? -1e30f : 0.f;
  }

  // ---- pass 2: c = softmax_j(u.w + mv); out = del ? 0 : squash(s2) -------
#pragma unroll
  for (int j = 0; j < J_; ++j) acc[j] = make_float4(0.f, 0.f, 0.f, 0.f);
#pragma unroll
  for (int p = 0; p < STEPS; p += 2) {
    if (p + 1 < STEPS) load_tile(base, (p + 1) * ROWS + il, Bf);
    w_tile(A, wq, mvj, acc);
    if (p + 2 < STEPS) load_tile(base, (p + 2) * ROWS + il, A);
    if (p + 1 < STEPS) w_tile(Bf, wq, mvj, acc);
  }
  block_reduce(acc, red, tid);
  if (tid < J_ * N_) {
    const int j = tid >> 4, n = tid & 15;
    const float s2 = red_sum(red, j, n) + bias[j * N_ + n];
    const float v2 = squash16(s2);
    const bool del = avg[j] < thr_s;
    out[(b * J_ + j) * N_ + n] = del ? 0.f : v2;
  }
}

extern "C" void kernel_launch(void* const* d_in, const int* in_sizes, int n_in,
                              void* d_out, int out_size, void* d_ws,
                              size_t ws_size, hipStream_t stream) {
  const float* u = (const float*)d_in[0];     // [B,J,I,N]
  const float* bias = (const float*)d_in[1];  // [J,N]
  // d_in[2] = iters (always 3; structure hardcoded)
  float* out = (float*)d_out;
  routing_one<<<B_, TPB, 0, stream>>>(u, bias, out);
}

// Round 9
// 277.391 us; speedup vs baseline: 1.0649x; 1.0637x over previous
//
#include <hip/hip_runtime.h>
#include <math.h>

// Problem constants (fixed by the reference).
#define B_ 256
#define J_ 10
#define I_ 1152
#define N_ 16
#define TPB 512     // 8 waves; one block per batch element; grid = 256 = 1/CU
#define STEPS 18    // 64 i-rows per step
#define CHUNK_F (2 * I_ * N_)  // floats between j-pairs (j,j+1) in u
#define STEPF (64 * N_)        // floats per 64-row step stride
#define WBUF 1280              // floats per wave staging buffer (5 KB)

typedef const __attribute__((address_space(1))) void* gas_t;
typedef __attribute__((address_space(3))) void* las_t;

template <int NV>
__device__ __forceinline__ void waitvm() {
  asm volatile("s_waitcnt vmcnt(%0)" ::"i"(NV) : "memory");
  __builtin_amdgcn_sched_barrier(0);
}
__device__ __forceinline__ void waitlgkm0() {
  asm volatile("s_waitcnt lgkmcnt(0)" ::: "memory");
  __builtin_amdgcn_sched_barrier(0);
}

// Stage one 64-row step for this wave: 5 x global_load_lds (16B/lane), 1 KB
// each, covering j = 2k,2k+1 x 8 rows x 4 quads. LDS dest is wave-uniform
// base + lane*16 (linear); global source is per-lane (matches layout).
__device__ __forceinline__ void stage(const float* __restrict__ g0,
                                      float* __restrict__ lw, int step) {
#pragma unroll
  for (int k = 0; k < 5; ++k) {
    __builtin_amdgcn_global_load_lds(
        (gas_t)(g0 + (size_t)k * CHUNK_F + (size_t)step * STEPF),
        (las_t)(lw + k * 256), 16, 0, 0);
  }
}

// Read this thread's 5 j-fragments (float4 each) of its row/quad from LDS.
__device__ __forceinline__ void read_tile(const float* __restrict__ lw, int jh,
                                          int rc, int q, float4* t) {
#pragma unroll
  for (int jj = 0; jj < 5; ++jj) {
    const int j = jh * 5 + jj;
    t[jj] = *(const float4*)(lw + (j >> 1) * 256 + (j & 1) * 128 + rc * 16 +
                             q * 4);
  }
}

__device__ __forceinline__ void sum_tile5(const float4* t, float4* acc) {
#pragma unroll
  for (int jj = 0; jj < 5; ++jj) {
    acc[jj].x += t[jj].x;
    acc[jj].y += t[jj].y;
    acc[jj].z += t[jj].z;
    acc[jj].w += t[jj].w;
  }
}

// acc[jj] += softmax_j(u.w + mv) * u. Each thread owns 5 j's (half); the
// denominator is combined with the partner half via shfl_xor(.,4).
// No max-subtract: |u.w| = O(10) << 88; masked j (mv=-1e30) -> exp = 0.
__device__ __forceinline__ void w_tile5(const float4* t, const float4* wq,
                                        const float* mvj, float4* acc) {
  float e[5];
  float se = 0.f;
#pragma unroll
  for (int jj = 0; jj < 5; ++jj) {
    float d = t[jj].x * wq[jj].x + t[jj].y * wq[jj].y + t[jj].z * wq[jj].z +
              t[jj].w * wq[jj].w;
    d += __shfl_xor(d, 1);  // sum 4 quads -> full 16-dot
    d += __shfl_xor(d, 2);
    e[jj] = __expf(d + mvj[jj]);
    se += e[jj];
  }
  se += __shfl_xor(se, 4);  // combine the two j-halves
  const float inv = 1.f / se;
#pragma unroll
  for (int jj = 0; jj < 5; ++jj) {
    const float c = e[jj] * inv;
    acc[jj].x = fmaf(c, t[jj].x, acc[jj].x);
    acc[jj].y = fmaf(c, t[jj].y, acc[jj].y);
    acc[jj].z = fmaf(c, t[jj].z, acc[jj].z);
    acc[jj].w = fmaf(c, t[jj].w, acc[jj].w);
  }
}

// One full streaming pass over u_hat, double-buffered, no barriers (buffers
// are wave-private). MODE 0: plain sum; MODE 1: softmax-weighted.
template <int MODE>
__device__ __forceinline__ void run_pass(const float* __restrict__ g0,
                                         float* __restrict__ lA,
                                         float* __restrict__ lB, int jh, int rc,
                                         int q, const float4* wq,
                                         const float* mvj, float4* acc) {
#pragma unroll
  for (int jj = 0; jj < 5; ++jj) acc[jj] = make_float4(0.f, 0.f, 0.f, 0.f);
  float4 t[5];
  stage(g0, lA, 0);
  stage(g0, lB, 1);
#define HALF(LBUF, NEXTP, VMC)                       \
  waitvm<VMC>();                                     \
  read_tile(LBUF, jh, rc, q, t);                     \
  waitlgkm0();                                       \
  if ((NEXTP) < STEPS) stage(g0, LBUF, (NEXTP));     \
  if (MODE == 0)                                     \
    sum_tile5(t, acc);                               \
  else                                               \
    w_tile5(t, wq, mvj, acc);
#define STEP2(P)                                     \
  { HALF(lA, (P) + 2, 5) }                           \
  { HALF(lB, (P) + 3, (((P) + 2 < STEPS) ? 5 : 0)) }
  STEP2(0) STEP2(2) STEP2(4) STEP2(6) STEP2(8) STEP2(10) STEP2(12) STEP2(14)
  STEP2(16)
#undef STEP2
#undef HALF
}

// Reduce acc (5 x float4 per thread; rows within wave) into red[w][jh][jj][16].
__device__ __forceinline__ void block_reduce5(const float4* acc,
                                              float* __restrict__ red, int wv,
                                              int lane, int jh, int q) {
#pragma unroll
  for (int jj = 0; jj < 5; ++jj) {
    float4 a = acc[jj];
#pragma unroll
    for (int off = 8; off < 64; off <<= 1) {
      a.x += __shfl_xor(a.x, off);
      a.y += __shfl_xor(a.y, off);
      a.z += __shfl_xor(a.z, off);
      a.w += __shfl_xor(a.w, off);
    }
    if (lane < 8) {  // lane = jh*4 + q
      float* dst = &red[(((wv << 1) + jh) * 5 + jj) * 16 + q * 4];
      dst[0] = a.x;
      dst[1] = a.y;
      dst[2] = a.z;
      dst[3] = a.w;
    }
  }
  __syncthreads();
}

__device__ __forceinline__ float sum8(const float* __restrict__ red, int j,
                                      int n) {
  const int jh = (j >= 5) ? 1 : 0;
  const int jj = j - jh * 5;
  float s = 0.f;
#pragma unroll
  for (int w = 0; w < 8; ++w) s += red[(((w << 1) + jh) * 5 + jj) * 16 + n];
  return s;
}

__device__ __forceinline__ float squash16(float s) {
  // 16 pose components live in a 16-lane group (n = lane&15).
  float sq = s * s;
  sq += __shfl_xor(sq, 1);
  sq += __shfl_xor(sq, 2);
  sq += __shfl_xor(sq, 4);
  sq += __shfl_xor(sq, 8);
  return (sq / (1.f + sq)) * s * rsqrtf(sq + 1e-8f);
}

__device__ __forceinline__ float4 ld4(const float* p) {
  return *(const float4*)p;
}

__global__ __launch_bounds__(TPB) void routing_one(
    const float* __restrict__ u, const float* __restrict__ bias,
    float* __restrict__ out) {
  const int tid = threadIdx.x;
  const int lane = tid & 63;
  const int wv = tid >> 6;
  // compute roles
  const int q = lane & 3;          // n-quad
  const int jh = (lane >> 2) & 1;  // j-half (0: j=0..4, 1: j=5..9)
  const int rc = lane >> 3;        // local row 0..7
  // loader roles
  const int jw = lane >> 5;        // j within pair
  const int rl = (lane >> 2) & 7;  // local row for load
  const int b = blockIdx.x;

  __shared__ __align__(16) float bufA[8 * WBUF];  // 40 KB
  __shared__ __align__(16) float bufB[8 * WBUF];  // 40 KB
  __shared__ float red[8 * 2 * 5 * 16];           // 5 KB
  __shared__ float wsh[J_ * N_];
  __shared__ float v0sh[J_ * N_];
  __shared__ float S0sh[J_ * N_];
  __shared__ float avg[J_];
  __shared__ float thr_s;

  const float* g0 = u + (size_t)b * J_ * I_ * N_ +
                    ((size_t)jw * I_ + (size_t)wv * 8 + rl) * N_ + q * 4;
  float* lA = bufA + wv * WBUF;
  float* lB = bufB + wv * WBUF;

  float4 acc[5], wq[5];
  float mvj[5];
#pragma unroll
  for (int jj = 0; jj < 5; ++jj) mvj[jj] = 0.f;

  // ---- pass 0: S0 = sum_i u ; v0 = squash(S0/J + bias) -------------------
  run_pass<0>(g0, lA, lB, jh, rc, q, wq, mvj, acc);
  block_reduce5(acc, red, wv, lane, jh, q);
  if (tid < J_ * N_) {
    const int j = tid >> 4, n = tid & 15;
    const float S0 = sum8(red, j, n);
    S0sh[tid] = S0;
    const float v0 = squash16(S0 * (1.f / (float)J_) + bias[j * N_ + n]);
    v0sh[tid] = v0;
    wsh[tid] = v0;
  }
  __syncthreads();
#pragma unroll
  for (int jj = 0; jj < 5; ++jj)
    wq[jj] = ld4(&wsh[(jh * 5 + jj) * N_ + q * 4]);

  // ---- pass 1: c = softmax_j(u.v0); v1 = squash(s1+bias); threshold ------
  run_pass<1>(g0, lA, lB, jh, rc, q, wq, mvj, acc);
  block_reduce5(acc, red, wv, lane, jh, q);
  if (tid < J_ * N_) {
    const int j = tid >> 4, n = tid & 15;
    const float s1 = sum8(red, j, n) + bias[j * N_ + n];
    const float v1 = squash16(s1);
    const float w2 = v0sh[tid] + v1;
    wsh[tid] = w2;
    float pa = S0sh[tid] * w2;
    pa += __shfl_xor(pa, 1);
    pa += __shfl_xor(pa, 2);
    pa += __shfl_xor(pa, 4);
    pa += __shfl_xor(pa, 8);
    if (n == 0) avg[j] = pa * (1.f / (float)I_);
  }
  __syncthreads();
  if (tid == 0) {
    float a = avg[0];
    for (int jj = 1; jj < J_; ++jj) a = fmaxf(a, avg[jj]);
    float se = 0.f;
    for (int jj = 0; jj < J_; ++jj) se += expf(avg[jj] - a);
    thr_s = logf(0.1f) + a + logf(se);
  }
  __syncthreads();
#pragma unroll
  for (int jj = 0; jj < 5; ++jj) {
    const int j = jh * 5 + jj;
    wq[jj] = ld4(&wsh[j * N_ + q * 4]);
    mvj[jj] = (avg[j] < thr_s) ? -1e30f : 0.f;
  }

  // ---- pass 2: c = softmax_j(u.w + mv); out = del ? 0 : squash(s2) -------
  run_pass<1>(g0, lA, lB, jh, rc, q, wq, mvj, acc);
  block_reduce5(acc, red, wv, lane, jh, q);
  if (tid < J_ * N_) {
    const int j = tid >> 4, n = tid & 15;
    const float s2 = sum8(red, j, n) + bias[j * N_ + n];
    const float v2 = squash16(s2);
    const bool del = avg[j] < thr_s;
    out[(b * J_ + j) * N_ + n] = del ? 0.f : v2;
  }
}

extern "C" void kernel_launch(void* const* d_in, const int* in_sizes, int n_in,
                              void* d_out, int out_size, void* d_ws,
                              size_t ws_size, hipStream_t stream) {
  const float* u = (const float*)d_in[0];     // [B,J,I,N]
  const float* bias = (const float*)d_in[1];  // [J,N]
  // d_in[2] = iters (always 3; structure hardcoded)
  float* out = (float*)d_out;
  routing_one<<<B_, TPB, 0, stream>>>(u, bias, out);
}